// Round 2
// baseline (1430.205 us; speedup 1.0000x reference)
//
#include <hip/hip_runtime.h>

// Linformer attention on MI355X (gfx950) — ROUND 2: conservative fp32 diagnostic.
// B=8 H=16 N=4096 DH=64 K=128 D=1024.
//
// Purpose: R1 (MFMA split-bf16) failed with absmax 21.5 ~= sqrt(2)*max|ref| —
// decorrelated output, i.e. a structural failure whose cause survives paper
// proof. This round removes EVERY exotic element: no MFMA, no bf16, no LDS
// overlays, no lane-layout bookkeeping. Pure fp32 VALU with simple LDS tiles.
// If this passes, the I/O-dtype / reshape / workspace assumptions are
// validated and MFMA gets reintroduced stage-by-stage next rounds.
//
// Layout facts (from the reference's reshape-then-transpose):
//   q(b,h,n,dh)  = queries_flat[((b*4096 + n)*16 + h)*64 + dh]
//   kk(b,h,k,dh) = keys_p[b][k][h*64+dh],  vv likewise from vals_p
//   out(b,h,n,dh) -> out_flat[(b*4096+n)*1024 + h*64 + dh]

#define Bb 8
#define Hh 16
#define Nn 4096
#define DHh 64
#define Kk 128
#define Dd 1024

typedef __attribute__((ext_vector_type(4))) float float4v;

// ---------------- stage 1: projection GEMMs (pure fp32) ----------------
// out_p[b][k][d] = sum_n X[b][n][d] * P[n][k]
// grid 512: x<256 -> keys/proj_k -> kp ; x>=256 -> values/proj_v -> vp.
// block tile: 32k x 128d ; thread owns 4k x 4d. n reduced in chunks of 32.
__global__ __launch_bounds__(256) void lfa1_f32(
    const float* __restrict__ keys, const float* __restrict__ values,
    const float* __restrict__ proj_k, const float* __restrict__ proj_v,
    float* __restrict__ kp, float* __restrict__ vp) {
  const bool vals = (int)blockIdx.x >= 256;
  const int id = (int)blockIdx.x & 255;
  const int b = id >> 5;                 // 0..7
  const int k0 = ((id >> 3) & 3) * 32;   // 0..96
  const int d0 = (id & 7) * 128;         // 0..896
  const float* __restrict__ Pg = vals ? proj_v : proj_k;                       // [4096][128]
  const float* __restrict__ Xg = (vals ? values : keys) + (size_t)b * Nn * Dd; // [4096][1024]
  float* __restrict__ dst = vals ? vp : kp;

  __shared__ alignas(16) float Ps[32 * 40];   // [n][k0..k0+32), stride 40 (160B)
  __shared__ alignas(16) float Xs[32 * 136];  // [n][d0..d0+128), stride 136 (544B)

  const int t = (int)threadIdx.x;
  const int kg = t >> 5;   // 0..7  -> k_local = kg*4 + a
  const int dg = t & 31;   // 0..31 -> d_local = dg*4 + c

  float acc[4][4];
#pragma unroll
  for (int a = 0; a < 4; ++a)
#pragma unroll
    for (int c = 0; c < 4; ++c) acc[a][c] = 0.f;

  float4v* const Ps4 = (float4v*)Ps;
  float4v* const Xs4 = (float4v*)Xs;

  for (int ck = 0; ck < Nn / 32; ++ck) {
    const int nb = ck * 32;
    {
      // Ps: 32n x 32k = 1024 floats = 256 threads x float4
      const int n = t >> 3, k4 = t & 7;
      Ps4[n * 10 + k4] = *(const float4v*)(Pg + (size_t)(nb + n) * Kk + k0 + k4 * 4);
      // Xs: 32n x 128d = 4096 floats = 4 passes
#pragma unroll
      for (int i = 0; i < 4; ++i) {
        const int s = i * 256 + t;
        const int nx = s >> 5, d4 = s & 31;
        Xs4[nx * 34 + d4] = *(const float4v*)(Xg + (size_t)(nb + nx) * Dd + d0 + d4 * 4);
      }
    }
    __syncthreads();
#pragma unroll 8
    for (int n = 0; n < 32; ++n) {
      const float4v pv = Ps4[n * 10 + kg];
      const float4v xv = Xs4[n * 34 + dg];
#pragma unroll
      for (int a = 0; a < 4; ++a)
#pragma unroll
        for (int c = 0; c < 4; ++c) acc[a][c] = fmaf(pv[a], xv[c], acc[a][c]);
    }
    __syncthreads();
  }

#pragma unroll
  for (int a = 0; a < 4; ++a) {
    float4v o = {acc[a][0], acc[a][1], acc[a][2], acc[a][3]};
    *(float4v*)(dst + (size_t)(b * Kk + k0 + kg * 4 + a) * Dd + d0 + dg * 4) = o;
  }
}

// ---------------- stage 2: attention (pure fp32) ----------------
// grid 8192 = B*H*(N/64). block: 64 q-rows of one (b,h).
// Phases: stage kk/vv slices -> dots to LDS -> row softmax (1 thread/row)
// -> PV -> store. All row/col indexing is thread-arithmetic, no MFMA layouts.
__global__ __launch_bounds__(256) void lfa2_f32(
    const float* __restrict__ q, const float* __restrict__ kp,
    const float* __restrict__ vp, float* __restrict__ out) {
  const int x = (int)blockIdx.x;
  const int n0 = (x & 63) * 64;
  const int h = (x >> 6) & 15;
  const int b = x >> 10;

  __shared__ alignas(16) float kks[128 * 68];  // [k][dh], stride 68 (272B)
  __shared__ alignas(16) float vvs[128 * 68];
  __shared__ alignas(16) float ds[64 * 132];   // [row][k] logits then probs

  const int t = (int)threadIdx.x;
  float4v* const kks4 = (float4v*)kks;
  float4v* const vvs4 = (float4v*)vvs;

  // stage kk/vv: 128k x 64dh = 2048 float4s each
#pragma unroll
  for (int i = 0; i < 8; ++i) {
    const int s = i * 256 + t;
    const int k = s >> 4, d4 = s & 15;
    const size_t off = (size_t)(b * Kk + k) * Dd + h * DHh + d4 * 4;
    kks4[k * 17 + d4] = *(const float4v*)(kp + off);
    vvs4[k * 17 + d4] = *(const float4v*)(vp + off);
  }
  __syncthreads();

  const float SC = 0.18033688011112042f;  // (1/8)*log2(e) folded into q
  // dots: thread = (row r = t>>2, k-quarter tk = t&3)
  {
    const int r = t >> 2, tk = t & 3;
    float4v q4[16];
#pragma unroll
    for (int i = 0; i < 16; ++i) {
      float4v v = *(const float4v*)(q + (((size_t)b * Nn + n0 + r) * Hh + h) * DHh + i * 4);
      q4[i] = v * SC;
    }
    for (int k = tk * 32; k < tk * 32 + 32; ++k) {
      float4v a = {0.f, 0.f, 0.f, 0.f};
#pragma unroll
      for (int i = 0; i < 16; ++i) {
        const float4v kv = kks4[k * 17 + i];
#pragma unroll
        for (int e = 0; e < 4; ++e) a[e] = fmaf(q4[i][e], kv[e], a[e]);
      }
      ds[r * 132 + k] = (a[0] + a[1]) + (a[2] + a[3]);  // logit * log2e
    }
  }
  __syncthreads();

  // softmax: one thread per row, fully serial (layout-agnostic)
  if (t < 64) {
    const int r = t;
    float m = -3.4e38f;
    for (int k = 0; k < Kk; ++k) m = fmaxf(m, ds[r * 132 + k]);
    float l = 0.f;
    for (int k = 0; k < Kk; ++k) l += exp2f(ds[r * 132 + k] - m);
    const float inv = 1.f / l;
    for (int k = 0; k < Kk; ++k) ds[r * 132 + k] = exp2f(ds[r * 132 + k] - m) * inv;
  }
  __syncthreads();

  // PV: thread = (row r = t>>2, dh-quarter dq = t&3); out[r][dq*16 .. +16)
  {
    const int r = t >> 2, dq = t & 3;
    float4v o4[4];
#pragma unroll
    for (int j = 0; j < 4; ++j) o4[j] = (float4v){0.f, 0.f, 0.f, 0.f};
    for (int k = 0; k < Kk; ++k) {
      const float p = ds[r * 132 + k];
#pragma unroll
      for (int j = 0; j < 4; ++j) {
        const float4v vv = vvs4[k * 17 + dq * 4 + j];
#pragma unroll
        for (int e = 0; e < 4; ++e) o4[j][e] = fmaf(p, vv[e], o4[j][e]);
      }
    }
    float* const op = out + ((size_t)b * Nn + n0 + r) * Dd + h * DHh + dq * 16;
#pragma unroll
    for (int j = 0; j < 4; ++j) *(float4v*)(op + j * 4) = o4[j];
  }
}

extern "C" void kernel_launch(void* const* d_in, const int* in_sizes, int n_in,
                              void* d_out, int out_size, void* d_ws, size_t ws_size,
                              hipStream_t stream) {
  (void)in_sizes; (void)n_in; (void)out_size; (void)ws_size;
  const float* queries = (const float*)d_in[0];
  const float* keys = (const float*)d_in[1];
  const float* values = (const float*)d_in[2];
  const float* proj_k = (const float*)d_in[3];
  const float* proj_v = (const float*)d_in[4];
  float* out = (float*)d_out;

  // ws: kp fp32 [8][128][1024] (4MB) | vp fp32 (4MB)
  float* kp = (float*)d_ws;
  float* vp = kp + (size_t)Bb * Kk * Dd;

  hipLaunchKernelGGL(lfa1_f32, dim3(512), dim3(256), 0, stream,
                     keys, values, proj_k, proj_v, kp, vp);
  hipLaunchKernelGGL(lfa2_f32, dim3(8192), dim3(256), 0, stream,
                     queries, kp, vp, out);
}